// Round 7
// baseline (69771.021 us; speedup 1.0000x reference)
//
#include <hip/hip_runtime.h>

// Seq2Seq LSTM H=128: enc 8192 + dec 4096 strictly sequential steps.
// Single block, one CU, 512 threads (8 waves). ONE barrier per step.
//
// R15. R14 post-mortem: reader/writer XOR relocation left
// SQ_LDS_BANK_CONFLICT bit-identical (192/step) -> conflict count is
// invariant under 32B-block relocation (4 start quads, 16 lanes/quad
// under any bijection). XOR reverted.
//
// R15 change — exchange via native LDS float atomics:
//  * Writer: 8x unsafeAtomicAdd -> ds_add_f32 (no-return) into the
//    GLOBAL row slot = 5*(r&127) + (r>>7) (= 5*lane + SOFF[s], banks
//    exactly 2-way free: 5 coprime 32). Adds execute in the LDS pipe
//    under MATVEC issue; 8 adds/slot arrive staggered (no burst).
//    NOTE: R12's 12x regression was SAFE atomicAdd -> CAS loop;
//    unsafeAtomicAdd is the documented ds_add_f32 path.
//  * Reader: ONE ds_read_b32 at prd + re-zero (replaces 2x b128 +
//    7-add tree): serial chain -25 cyc, -7 VALU/lane.
//  * Race-free via parity double-buffer: reader zero of step st
//    drains (lgkmcnt) at barrier st+1, before parity reuse at st+2.
//  * Keeps R13/R14: s-pair pk_fma, pk_mul first-iter, exp2-folded
//    branchless nonlin, post-barrier OUTBLK, 2-step unroll.

#define H      128
#define ENC_T  8192
#define DEC_T  4096
#define NT     512
#define NBLK   1
#define PBUF   640          // row slots: prd <= 638

#define LOG2E  1.4426950408889634f

typedef float v2f __attribute__((ext_vector_type(2)));

__device__ __forceinline__ v2f pk_fma_s(v2f a, v2f b_sgpr, v2f c) {
    v2f d;   // b is wave-uniform: read as 64-bit scalar operand (s-pair)
    asm("v_pk_fma_f32 %0, %1, %2, %3" : "=v"(d) : "v"(a), "s"(b_sgpr), "v"(c));
    return d;
}
__device__ __forceinline__ v2f pk_mul_s(v2f a, v2f b_sgpr) {
    v2f d;   // first-iteration accumulator: acc = w*h (no zero-init)
    asm("v_pk_mul_f32 %0, %1, %2" : "=v"(d) : "v"(a), "s"(b_sgpr));
    return d;
}
__device__ __forceinline__ v2f pk_fma(v2f a, v2f b, v2f c) {
    v2f d;
    asm("v_pk_fma_f32 %0, %1, %2, %3" : "=v"(d) : "v"(a), "v"(b), "v"(c));
    return d;
}
__device__ __forceinline__ float exp2fast(float x) {   // raw v_exp_f32 (2^x)
    float d;
    asm("v_exp_f32 %0, %1" : "=v"(d) : "v"(x));
    return d;
}
__device__ __forceinline__ float tanhfast(float x) {   // 1 - 2/(1+2^(2*log2e*x))
    const float e = exp2fast(2.0f * LOG2E * x);
    return fmaf(-2.0f, __builtin_amdgcn_rcpf(1.0f + e), 1.0f);
}
__device__ __forceinline__ float rdlane(float v, int l) {
    return __int_as_float(__builtin_amdgcn_readlane(__float_as_int(v), l));
}
template <int CTRL>
__device__ __forceinline__ float qperm(float v) {      // DPP quad_perm, VALU-speed
    return __int_as_float(
        __builtin_amdgcn_mov_dpp(__float_as_int(v), CTRL, 0xf, 0xf, true));
}

__global__ __launch_bounds__(NT, 2)
void seq2seq_lstm(const float* __restrict__ input_seq,
                  const float* __restrict__ enc_Wih,
                  const float* __restrict__ enc_Whh,
                  const float* __restrict__ enc_bih,
                  const float* __restrict__ enc_bhh,
                  const float* __restrict__ dec_Wih,
                  const float* __restrict__ dec_Whh,
                  const float* __restrict__ dec_bih,
                  const float* __restrict__ dec_bhh,
                  const float* __restrict__ fc_W,
                  const float* __restrict__ fc_b,
                  float* __restrict__ out,
                  unsigned* __restrict__ wsflag)
{
    (void)wsflag;
    __shared__ __align__(16) float xin[ENC_T];          // 32 KB
    __shared__ __align__(16) float hbuf[2][H];          // h history (off-path)
    __shared__ __align__(16) float part[2][PBUF];       // dbl-buffered row sums

    const int t    = threadIdx.x;      // 0..511
    const int lane = t & 63;
    const int wv   = t >> 6;           // wave 0..7, j-slice [16wv,16wv+16)
    const int jb   = 16 * wv;
    const int qq   = lane >> 2;        // reduce role: unit-in-slice 0..15
    const int g    = lane & 3;         // gate 0=i 1=f 2=g 3=o
    const int myu  = jb + qq;          // my unit (global)
    const int myrow = g * H + myu;     // my gate row
    const int prd  = 5 * myu + g;      // my row-sum slot
    const int pw5  = 5 * lane;         // writer base slot

    // branchless nonlin constants (log2e pre-folded):
    // g==2 -> tanh-form, else sigmoid-form
    const float sA  = (g == 2) ? 1.0f : 0.0f;
    const float sB  = (g == 2) ? -2.0f : 1.0f;
    const float sS2 = ((g == 2) ? 2.0f : -1.0f) * LOG2E;

    {   // zero row-sum accumulators (both parities) before first use
        float* p0 = (float*)part;
        for (int i = t; i < 2 * PBUF; i += NT) p0[i] = 0.f;
    }
    {   // stage input sequence
        const float4* s = (const float4*)input_seq;
        float4* d = (float4*)xin;
        for (int i = t; i < ENC_T / 4; i += NT) d[i] = s[i];
    }

    // matvec weights as j-pairs: w2[s][jj] = Whh[(64s+lane)][jb+2jj, jb+2jj+1]
    v2f w2[8][8];
#pragma unroll
    for (int s = 0; s < 8; ++s) {
        const v2f* Wr = (const v2f*)(enc_Whh + (64 * s + lane) * H + jb);
#pragma unroll
        for (int jj = 0; jj < 8; ++jj) w2[s][jj] = Wr[jj];
    }
    float bias_r = enc_bih[myrow] + enc_bhh[myrow];
    float wih_r  = enc_Wih[myrow];

    float cst = 0.f;      // cell state of unit myu (replicated per quad)
    float hn  = 0.f;      // h of unit myu (replicated per quad)
    __syncthreads();

    // h[jb+2jj+c] lives in quad 2jj+c of this wave -> g==3 lane 8jj+4c+3
    // row 64s+lane -> global slot pw5 + SOFF[s], SOFF = 320(s&1)+(s>>1)
#define MATVEC(PB)                                                          \
    {                                                                       \
        v2f acc2[8];                                                        \
        {   /* jj = 0: pk_mul, no accumulator init */                       \
            const float se = rdlane(hn, 3);                                 \
            const float so = rdlane(hn, 7);                                 \
            const v2f hp = {se, so};                                        \
            _Pragma("unroll") for (int s = 0; s < 8; ++s)                   \
                acc2[s] = pk_mul_s(w2[s][0], hp);                           \
        }                                                                   \
        _Pragma("unroll") for (int jj = 1; jj < 8; ++jj) {                  \
            const float se = rdlane(hn, 8 * jj + 3);                        \
            const float so = rdlane(hn, 8 * jj + 7);                        \
            const v2f hp = {se, so};                                        \
            _Pragma("unroll") for (int s = 0; s < 8; ++s)                   \
                acc2[s] = pk_fma_s(w2[s][jj], hp, acc2[s]);                 \
        }                                                                   \
        float* pb_ = &part[PB][pw5];                                        \
        unsafeAtomicAdd(pb_ + 0,   acc2[0].x + acc2[0].y);                  \
        unsafeAtomicAdd(pb_ + 320, acc2[1].x + acc2[1].y);                  \
        unsafeAtomicAdd(pb_ + 1,   acc2[2].x + acc2[2].y);                  \
        unsafeAtomicAdd(pb_ + 321, acc2[3].x + acc2[3].y);                  \
        unsafeAtomicAdd(pb_ + 2,   acc2[4].x + acc2[4].y);                  \
        unsafeAtomicAdd(pb_ + 322, acc2[5].x + acc2[5].y);                  \
        unsafeAtomicAdd(pb_ + 3,   acc2[6].x + acc2[6].y);                  \
        unsafeAtomicAdd(pb_ + 323, acc2[7].x + acc2[7].y);                  \
    }

    // read my final row sum, then re-zero the slot (reused 2 steps later;
    // safe: this zero is lgkm-drained at the NEXT barrier, before reuse)
#define RED_LOAD(PB)                                                        \
    const float a8_ = part[PB][prd];                                        \
    part[PB][prd] = 0.f;

    // STH: 1 -> store h to hbuf[PB] (decoder out reads stale hbuf)
#define RED_FIN(PB, ABASE, STH)                                             \
    {                                                                       \
        const float a = (ABASE) + a8_;                                      \
        const float e = exp2fast(sS2 * a);                                  \
        const float r = __builtin_amdgcn_rcpf(1.0f + e);                    \
        const float v = fmaf(sB, r, sA);                                    \
        const float vi = qperm<0x00>(v);   /* quad lane 0 */                \
        const float vf = qperm<0x55>(v);   /* quad lane 1 */                \
        const float vg = qperm<0xAA>(v);   /* quad lane 2 */                \
        const float vo = qperm<0xFF>(v);   /* quad lane 3 */                \
        cst = fmaf(vf, cst, vi * vg);                                       \
        hn  = vo * tanhfast(cst);                                           \
        if (STH && g == 3) hbuf[PB][myu] = hn;                              \
    }

    // post-barrier fc output: out[ST-1] from hbuf[HB] (= h after step ST-1;
    // stable: this step's REDUCE writes hbuf[1-HB]). Runs in wave 7's
    // part-read latency shadow.
#define OUTBLK(ST, HB)                                                      \
    if (wv == 7 && (ST) >= 1) {                                             \
        float p = fmaf(fwl, hbuf[HB][lane], fwh * hbuf[HB][64 + lane]);     \
        p += qperm<0xB1>(p);               /* xor 1 */                      \
        p += qperm<0x4E>(p);               /* xor 2 */                      \
        _Pragma("unroll") for (int m = 32; m >= 4; m >>= 1)                 \
            p += __shfl_xor(p, m, 64);                                      \
        if (lane == 0) out[(ST) - 1] = p + fcb;                             \
    }

    // ---------------- encoder: 8192 steps, ONE barrier each ----------------
    for (int st = 0; st < ENC_T; st += 2) {
        const float2 xx = *(const float2*)&xin[st];
        {
            MATVEC(0);
            __syncthreads();
            RED_LOAD(0);
            RED_FIN(0, fmaf(wih_r, xx.x, bias_r), 0);
        }
        {
            MATVEC(1);
            __syncthreads();
            RED_LOAD(1);
            RED_FIN(1, fmaf(wih_r, xx.y, bias_r), 0);
        }
    }
    if (g == 3) hbuf[1][myu] = hn;         // final encoder h, once

    // ---------------- decoder setup: fold fc into Whh ----------------
    const float fcb = fc_b[0];
    const float fwl = fc_W[lane];
    const float fwh = fc_W[64 + lane];
#pragma unroll
    for (int s = 0; s < 8; ++s) {
        const int r = 64 * s + lane;
        const float vi = dec_Wih[r];
        const v2f vip = {vi, vi};
        const v2f* Wr = (const v2f*)(dec_Whh + r * H + jb);
        const v2f* Fr = (const v2f*)(fc_W + jb);
#pragma unroll
        for (int jj = 0; jj < 8; ++jj)
            w2[s][jj] = pk_fma(vip, Fr[jj], Wr[jj]);   // W' = Whh + wih (x) fcW
    }
    wih_r  = dec_Wih[myrow];
    bias_r = dec_bih[myrow] + dec_bhh[myrow] + wih_r * fcb;
    __syncthreads();                       // h_enc visible in hbuf[1]
    float q0;
    {
        float p = fmaf(fwl, hbuf[1][lane], fwh * hbuf[1][64 + lane]);
        p += qperm<0xB1>(p);               // xor 1
        p += qperm<0x4E>(p);               // xor 2
#pragma unroll
        for (int m = 32; m >= 4; m >>= 1) p += __shfl_xor(p, m, 64);
        q0 = p + fcb;
    }
    float cb = bias_r - wih_r * q0;        // step-0 correction (y0 = 0)

    // ---------------- decoder: 4096 steps ----------------
    for (int st = 0; st < DEC_T; st += 2) {
        {   // even step ST=st: out[st-1] from hbuf[1] (odd-parity h)
            MATVEC(0);
            __syncthreads();
            RED_LOAD(0);
            OUTBLK(st, 1);
            RED_FIN(0, cb, 1);
            cb = bias_r;
        }
        {   // odd step ST=st+1: out[st] from hbuf[0]
            MATVEC(1);
            __syncthreads();
            RED_LOAD(1);
            OUTBLK(st + 1, 0);
            RED_FIN(1, cb, 1);
        }
    }

    // tail: out[DEC_T-1] from hbuf[1] (h after final step, parity 1)
    __syncthreads();
    if (wv == 7) {
        float p = fmaf(fwl, hbuf[1][lane], fwh * hbuf[1][64 + lane]);
        p += qperm<0xB1>(p);
        p += qperm<0x4E>(p);
#pragma unroll
        for (int m = 32; m >= 4; m >>= 1) p += __shfl_xor(p, m, 64);
        if (lane == 0) out[DEC_T - 1] = p + fcb;
    }
}

extern "C" void kernel_launch(void* const* d_in, const int* in_sizes, int n_in,
                              void* d_out, int out_size, void* d_ws, size_t ws_size,
                              hipStream_t stream)
{
    (void)in_sizes; (void)n_in; (void)ws_size; (void)out_size;
    seq2seq_lstm<<<NBLK, NT, 0, stream>>>(
        (const float*)d_in[0],   // input_seq
        (const float*)d_in[1],   // enc_Wih
        (const float*)d_in[2],   // enc_Whh
        (const float*)d_in[3],   // enc_bih
        (const float*)d_in[4],   // enc_bhh
        (const float*)d_in[5],   // dec_Wih
        (const float*)d_in[6],   // dec_Whh
        (const float*)d_in[7],   // dec_bih
        (const float*)d_in[8],   // dec_bhh
        (const float*)d_in[9],   // fc_W
        (const float*)d_in[10],  // fc_b
        (float*)d_out,
        (unsigned*)d_ws);
}

// Round 8
// 7515.683 us; speedup vs baseline: 9.2834x; 9.2834x over previous
//
#include <hip/hip_runtime.h>

// Seq2Seq LSTM H=128: enc 8192 + dec 4096 strictly sequential steps.
// Single block, one CU, 512 threads (8 waves). ONE barrier per step.
//
// R16. R15 post-mortem: unsafeAtomicAdd on LDS ALSO lowers to a CAS
// loop (SGPR 112->64 signature, 97 ms) -> hardware ds_add_f32 is
// unreachable from HIP here. LDS float atomics dead end (x2). Reverted.
//
// R13 budget rebuild with the LDS PIPE as a resource: exchange moves
// 16KB writes + 16KB reads/step. Post-barrier, all 8 waves issue their
// 2x ds_read_b128 at once: 128 cyc BW floor + 192 cyc/step measured
// conflicts (2.36M/12288; R14 proved invariant under block relocation:
// contiguous 8-float row blocks force start-quad = prd&3, 16 lanes/quad
// under ANY bijection). ~320 cyc of serialized reads on the critical
// path. 516 issue + 320 pipe + ~120 chain + ~75 barrier ~= 1032. ✓
//
// R16 change — TRANSPOSED partial layout (wave-major):
//   slot(w,row) = 640w + 80*wv_u + 16*g + qq
//  * Reader: 8x ds_read_b32, one base (80wv+16g+qq), imm offs 2560w.
//    Bank = (16wv + qq+16g)%32, qq+16g in 0..63 -> EXACT 2-way = free.
//  * Writer: base 640wv + 80*(l>>4) + (l&15), const dword offs
//    {0,320,16,336,32,352,48,368}; banks 0..63 mod 32 = 2-way free;
//    (0,16),(32,48) pairs are ds_write2_b32-mergeable.
//  * Coverage verified: writer slot == reader slot for row 64s+l.
//  * +6 read issues/lane vs -192 conflict -64 pipe cyc.
// Kept: s-pair pk_fma, pk_mul first-iter, exp2-folded branchless
// nonlin, post-barrier OUTBLK, 2-step unroll. R14 XOR reverted.

#define H      128
#define ENC_T  8192
#define DEC_T  4096
#define NT     512
#define NBLK   1
#define PBUF   5120         // floats per parity: slot max 5103

#define LOG2E  1.4426950408889634f

typedef float v2f __attribute__((ext_vector_type(2)));

__device__ __forceinline__ v2f pk_fma_s(v2f a, v2f b_sgpr, v2f c) {
    v2f d;   // b is wave-uniform: read as 64-bit scalar operand (s-pair)
    asm("v_pk_fma_f32 %0, %1, %2, %3" : "=v"(d) : "v"(a), "s"(b_sgpr), "v"(c));
    return d;
}
__device__ __forceinline__ v2f pk_mul_s(v2f a, v2f b_sgpr) {
    v2f d;   // first-iteration accumulator: acc = w*h (no zero-init)
    asm("v_pk_mul_f32 %0, %1, %2" : "=v"(d) : "v"(a), "s"(b_sgpr));
    return d;
}
__device__ __forceinline__ v2f pk_fma(v2f a, v2f b, v2f c) {
    v2f d;
    asm("v_pk_fma_f32 %0, %1, %2, %3" : "=v"(d) : "v"(a), "v"(b), "v"(c));
    return d;
}
__device__ __forceinline__ float exp2fast(float x) {   // raw v_exp_f32 (2^x)
    float d;
    asm("v_exp_f32 %0, %1" : "=v"(d) : "v"(x));
    return d;
}
__device__ __forceinline__ float tanhfast(float x) {   // 1 - 2/(1+2^(2*log2e*x))
    const float e = exp2fast(2.0f * LOG2E * x);
    return fmaf(-2.0f, __builtin_amdgcn_rcpf(1.0f + e), 1.0f);
}
__device__ __forceinline__ float rdlane(float v, int l) {
    return __int_as_float(__builtin_amdgcn_readlane(__float_as_int(v), l));
}
template <int CTRL>
__device__ __forceinline__ float qperm(float v) {      // DPP quad_perm, VALU-speed
    return __int_as_float(
        __builtin_amdgcn_mov_dpp(__float_as_int(v), CTRL, 0xf, 0xf, true));
}

__global__ __launch_bounds__(NT, 2)
void seq2seq_lstm(const float* __restrict__ input_seq,
                  const float* __restrict__ enc_Wih,
                  const float* __restrict__ enc_Whh,
                  const float* __restrict__ enc_bih,
                  const float* __restrict__ enc_bhh,
                  const float* __restrict__ dec_Wih,
                  const float* __restrict__ dec_Whh,
                  const float* __restrict__ dec_bih,
                  const float* __restrict__ dec_bhh,
                  const float* __restrict__ fc_W,
                  const float* __restrict__ fc_b,
                  float* __restrict__ out,
                  unsigned* __restrict__ wsflag)
{
    (void)wsflag;
    __shared__ __align__(16) float xin[ENC_T];          // 32 KB
    __shared__ __align__(16) float hbuf[2][H];          // h history (off-path)
    __shared__ __align__(16) float part[2][PBUF];       // dbl-buffered partials

    const int t    = threadIdx.x;      // 0..511
    const int lane = t & 63;
    const int wv   = t >> 6;           // wave 0..7, j-slice [16wv,16wv+16)
    const int jb   = 16 * wv;
    const int qq   = lane >> 2;        // reduce role: unit-in-slice 0..15
    const int g    = lane & 3;         // gate 0=i 1=f 2=g 3=o
    const int myu  = jb + qq;          // my unit (global)
    const int myrow = g * H + myu;     // my gate row

    // transposed exchange: slot(w,row) = 640w + 80*(u>>4) + 16*g + (u&15)
    const int rbase = 80 * wv + 16 * g + qq;            // reader base (w=0)
    const int wbase = 640 * wv + 80 * (lane >> 4) + (lane & 15); // writer base

    // branchless nonlin constants (log2e pre-folded):
    // g==2 -> tanh-form, else sigmoid-form
    const float sA  = (g == 2) ? 1.0f : 0.0f;
    const float sB  = (g == 2) ? -2.0f : 1.0f;
    const float sS2 = ((g == 2) ? 2.0f : -1.0f) * LOG2E;

    {   // stage input sequence
        const float4* s = (const float4*)input_seq;
        float4* d = (float4*)xin;
        for (int i = t; i < ENC_T / 4; i += NT) d[i] = s[i];
    }

    // matvec weights as j-pairs: w2[s][jj] = Whh[(64s+lane)][jb+2jj, jb+2jj+1]
    v2f w2[8][8];
#pragma unroll
    for (int s = 0; s < 8; ++s) {
        const v2f* Wr = (const v2f*)(enc_Whh + (64 * s + lane) * H + jb);
#pragma unroll
        for (int jj = 0; jj < 8; ++jj) w2[s][jj] = Wr[jj];
    }
    float bias_r = enc_bih[myrow] + enc_bhh[myrow];
    float wih_r  = enc_Wih[myrow];

    float cst = 0.f;      // cell state of unit myu (replicated per quad)
    float hn  = 0.f;      // h of unit myu (replicated per quad)
    __syncthreads();

    // h[jb+2jj+c] lives in quad 2jj+c of this wave -> g==3 lane 8jj+4c+3
    // row 64s+lane -> slot wbase + 320(s&1) + 16(s>>1)
#define MATVEC(PB)                                                          \
    {                                                                       \
        v2f acc2[8];                                                        \
        {   /* jj = 0: pk_mul, no accumulator init */                       \
            const float se = rdlane(hn, 3);                                 \
            const float so = rdlane(hn, 7);                                 \
            const v2f hp = {se, so};                                        \
            _Pragma("unroll") for (int s = 0; s < 8; ++s)                   \
                acc2[s] = pk_mul_s(w2[s][0], hp);                           \
        }                                                                   \
        _Pragma("unroll") for (int jj = 1; jj < 8; ++jj) {                  \
            const float se = rdlane(hn, 8 * jj + 3);                        \
            const float so = rdlane(hn, 8 * jj + 7);                        \
            const v2f hp = {se, so};                                        \
            _Pragma("unroll") for (int s = 0; s < 8; ++s)                   \
                acc2[s] = pk_fma_s(w2[s][jj], hp, acc2[s]);                 \
        }                                                                   \
        float* pb_ = &part[PB][wbase];                                      \
        pb_[0]   = acc2[0].x + acc2[0].y;                                   \
        pb_[320] = acc2[1].x + acc2[1].y;                                   \
        pb_[16]  = acc2[2].x + acc2[2].y;                                   \
        pb_[336] = acc2[3].x + acc2[3].y;                                   \
        pb_[32]  = acc2[4].x + acc2[4].y;                                   \
        pb_[352] = acc2[5].x + acc2[5].y;                                   \
        pb_[48]  = acc2[6].x + acc2[6].y;                                   \
        pb_[368] = acc2[7].x + acc2[7].y;                                   \
    }

    // 8x conflict-free ds_read_b32 (imm offsets 2560w), 7-add tree
#define RED_LOAD(PB)                                                        \
    const float* rb_ = &part[PB][rbase];                                    \
    const float r0_ = rb_[0],    r1_ = rb_[640],  r2_ = rb_[1280],          \
                r3_ = rb_[1920], r4_ = rb_[2560], r5_ = rb_[3200],          \
                r6_ = rb_[3840], r7_ = rb_[4480];

    // STH: 1 -> store h to hbuf[PB] (decoder out reads stale hbuf)
#define RED_FIN(PB, ABASE, STH)                                             \
    {                                                                       \
        const float a = (ABASE) + (((r0_ + r1_) + (r2_ + r3_)) +            \
                                   ((r4_ + r5_) + (r6_ + r7_)));            \
        const float e = exp2fast(sS2 * a);                                  \
        const float r = __builtin_amdgcn_rcpf(1.0f + e);                    \
        const float v = fmaf(sB, r, sA);                                    \
        const float vi = qperm<0x00>(v);   /* quad lane 0 */                \
        const float vf = qperm<0x55>(v);   /* quad lane 1 */                \
        const float vg = qperm<0xAA>(v);   /* quad lane 2 */                \
        const float vo = qperm<0xFF>(v);   /* quad lane 3 */                \
        cst = fmaf(vf, cst, vi * vg);                                       \
        hn  = vo * tanhfast(cst);                                           \
        if (STH && g == 3) hbuf[PB][myu] = hn;                              \
    }

    // post-barrier fc output: out[ST-1] from hbuf[HB] (= h after step ST-1;
    // stable: this step's REDUCE writes hbuf[1-HB]). Runs in wave 7's
    // part-read latency shadow.
#define OUTBLK(ST, HB)                                                      \
    if (wv == 7 && (ST) >= 1) {                                             \
        float p = fmaf(fwl, hbuf[HB][lane], fwh * hbuf[HB][64 + lane]);     \
        p += qperm<0xB1>(p);               /* xor 1 */                      \
        p += qperm<0x4E>(p);               /* xor 2 */                      \
        _Pragma("unroll") for (int m = 32; m >= 4; m >>= 1)                 \
            p += __shfl_xor(p, m, 64);                                      \
        if (lane == 0) out[(ST) - 1] = p + fcb;                             \
    }

    // ---------------- encoder: 8192 steps, ONE barrier each ----------------
    for (int st = 0; st < ENC_T; st += 2) {
        const float2 xx = *(const float2*)&xin[st];
        {
            MATVEC(0);
            __syncthreads();
            RED_LOAD(0);
            RED_FIN(0, fmaf(wih_r, xx.x, bias_r), 0);
        }
        {
            MATVEC(1);
            __syncthreads();
            RED_LOAD(1);
            RED_FIN(1, fmaf(wih_r, xx.y, bias_r), 0);
        }
    }
    if (g == 3) hbuf[1][myu] = hn;         // final encoder h, once

    // ---------------- decoder setup: fold fc into Whh ----------------
    const float fcb = fc_b[0];
    const float fwl = fc_W[lane];
    const float fwh = fc_W[64 + lane];
#pragma unroll
    for (int s = 0; s < 8; ++s) {
        const int r = 64 * s + lane;
        const float vi = dec_Wih[r];
        const v2f vip = {vi, vi};
        const v2f* Wr = (const v2f*)(dec_Whh + r * H + jb);
        const v2f* Fr = (const v2f*)(fc_W + jb);
#pragma unroll
        for (int jj = 0; jj < 8; ++jj)
            w2[s][jj] = pk_fma(vip, Fr[jj], Wr[jj]);   // W' = Whh + wih (x) fcW
    }
    wih_r  = dec_Wih[myrow];
    bias_r = dec_bih[myrow] + dec_bhh[myrow] + wih_r * fcb;
    __syncthreads();                       // h_enc visible in hbuf[1]
    float q0;
    {
        float p = fmaf(fwl, hbuf[1][lane], fwh * hbuf[1][64 + lane]);
        p += qperm<0xB1>(p);               // xor 1
        p += qperm<0x4E>(p);               // xor 2
#pragma unroll
        for (int m = 32; m >= 4; m >>= 1) p += __shfl_xor(p, m, 64);
        q0 = p + fcb;
    }
    float cb = bias_r - wih_r * q0;        // step-0 correction (y0 = 0)

    // ---------------- decoder: 4096 steps ----------------
    for (int st = 0; st < DEC_T; st += 2) {
        {   // even step ST=st: out[st-1] from hbuf[1] (odd-parity h)
            MATVEC(0);
            __syncthreads();
            RED_LOAD(0);
            OUTBLK(st, 1);
            RED_FIN(0, cb, 1);
            cb = bias_r;
        }
        {   // odd step ST=st+1: out[st] from hbuf[0]
            MATVEC(1);
            __syncthreads();
            RED_LOAD(1);
            OUTBLK(st + 1, 0);
            RED_FIN(1, cb, 1);
        }
    }

    // tail: out[DEC_T-1] from hbuf[1] (h after final step, parity 1)
    __syncthreads();
    if (wv == 7) {
        float p = fmaf(fwl, hbuf[1][lane], fwh * hbuf[1][64 + lane]);
        p += qperm<0xB1>(p);
        p += qperm<0x4E>(p);
#pragma unroll
        for (int m = 32; m >= 4; m >>= 1) p += __shfl_xor(p, m, 64);
        if (lane == 0) out[DEC_T - 1] = p + fcb;
    }
}

extern "C" void kernel_launch(void* const* d_in, const int* in_sizes, int n_in,
                              void* d_out, int out_size, void* d_ws, size_t ws_size,
                              hipStream_t stream)
{
    (void)in_sizes; (void)n_in; (void)ws_size; (void)out_size;
    seq2seq_lstm<<<NBLK, NT, 0, stream>>>(
        (const float*)d_in[0],   // input_seq
        (const float*)d_in[1],   // enc_Wih
        (const float*)d_in[2],   // enc_Whh
        (const float*)d_in[3],   // enc_bih
        (const float*)d_in[4],   // enc_bhh
        (const float*)d_in[5],   // dec_Wih
        (const float*)d_in[6],   // dec_Whh
        (const float*)d_in[7],   // dec_bih
        (const float*)d_in[8],   // dec_bhh
        (const float*)d_in[9],   // fc_W
        (const float*)d_in[10],  // fc_b
        (float*)d_out,
        (unsigned*)d_ws);
}